// Round 3
// baseline (626.037 us; speedup 1.0000x reference)
//
#include <hip/hip_runtime.h>
#include <hip/hip_bf16.h>
#include <cstdint>
#include <cstddef>

typedef __bf16 bf16_t;
typedef __bf16 bf16x8 __attribute__((ext_vector_type(8)));
typedef float f32x4 __attribute__((ext_vector_type(4)));

#define TOKENS 8192
#define IN_F 4096
#define OUT_F 4096

#define BM 128
#define BN 128
#define BK 32

// ---------------- dequant: packed nibbles -> bf16 W[OUT_F][IN_F] ----------
__global__ __launch_bounds__(256) void dequant_nf4(
    const int* __restrict__ qw, const int* __restrict__ am1,
    const float* __restrict__ cd1, const float* __restrict__ of1,
    const float* __restrict__ am2, const float* __restrict__ cd2,
    bf16_t* __restrict__ W) {
  const int t = blockIdx.x * 256 + threadIdx.x;
  const int e0 = t << 3;        // 8 dequantized elements per thread
  const int b1 = e0 >> 6;       // primary block (64 elems) -- all 8 share it
  const int b2 = e0 >> 8;       // secondary block (256 elems)
  const int4 v = *(const int4*)(qw + (t << 2));
  const float s2 = am2[b2] / cd2[b2];
  const float s1 = ((float)am1[b1] / cd1[b1]) * s2;
  const float off = of1[b1];
  int vv[4] = {v.x, v.y, v.z, v.w};
  bf16x8 w;
#pragma unroll
  for (int i = 0; i < 4; ++i) {
    // even linear offset = lower nibble, odd = upper nibble
    w[2 * i]     = (bf16_t)(((float)(vv[i] & 15) - off) * s1);
    w[2 * i + 1] = (bf16_t)(((float)((vv[i] >> 4) & 15) - off) * s1);
  }
  *(bf16x8*)(W + e0) = w;
}

// ---------------- GEMM: C[M,N] = X[M,K] * W[N,K]^T ------------------------
// X is FLOAT32 (harness lowers fp16 -> f32); converted to bf16 at staging.
// Output C is FLOAT32. W (from dequant scratch) is bf16.
__global__ __launch_bounds__(256) void gemm_xwt(
    const float* __restrict__ X, const bf16_t* __restrict__ W,
    float* __restrict__ C) {
  __shared__ __align__(16) bf16_t As[BM * BK];   // row-major [128][32]
  __shared__ __align__(16) bf16_t Bs[BN * BK];

  const int tid = threadIdx.x;
  const int lane = tid & 63;
  const int wid = tid >> 6;       // 4 waves
  const int m0 = blockIdx.y * BM;
  const int n0 = blockIdx.x * BN;

  // staging: tile = 128 rows x 32 k = 512 chunks of 8 elems; 2 chunks/thread
  const int srow = tid >> 2;            // 0..63
  const int sk = (tid & 3) << 3;        // 0,8,16,24
  const float* ag0 = X + (size_t)(m0 + srow) * IN_F + sk;
  const float* ag1 = ag0 + (size_t)64 * IN_F;
  const bf16_t* bg0 = W + (size_t)(n0 + srow) * IN_F + sk;
  const bf16_t* bg1 = bg0 + (size_t)64 * IN_F;
  bf16_t* as0 = As + srow * BK + sk;
  bf16_t* as1 = as0 + 64 * BK;
  bf16_t* bs0 = Bs + srow * BK + sk;
  bf16_t* bs1 = bs0 + 64 * BK;

  // wave 2x2 grid over the 128x128 tile; 4x4 MFMA tiles of 16x16 per wave
  const int wm = (wid >> 1) << 6;
  const int wn = (wid & 1) << 6;
  const int lr = lane & 15;
  const int quad = lane >> 4;

  f32x4 acc[4][4] = {};

  for (int k0 = 0; k0 < IN_F; k0 += BK) {
    // global loads into registers (before barrier, hides latency)
    f32x4 xa0 = *(const f32x4*)(ag0 + k0);
    f32x4 xa1 = *(const f32x4*)(ag0 + k0 + 4);
    f32x4 xb0 = *(const f32x4*)(ag1 + k0);
    f32x4 xb1 = *(const f32x4*)(ag1 + k0 + 4);
    bf16x8 rb0 = *(const bf16x8*)(bg0 + k0);
    bf16x8 rb1 = *(const bf16x8*)(bg1 + k0);

    bf16x8 ra0, ra1;
#pragma unroll
    for (int t = 0; t < 4; ++t) {
      ra0[t] = (bf16_t)xa0[t];
      ra0[t + 4] = (bf16_t)xa1[t];
      ra1[t] = (bf16_t)xb0[t];
      ra1[t + 4] = (bf16_t)xb1[t];
    }

    __syncthreads();   // previous iteration's LDS reads complete
    *(bf16x8*)as0 = ra0;
    *(bf16x8*)as1 = ra1;
    *(bf16x8*)bs0 = rb0;
    *(bf16x8*)bs1 = rb1;
    __syncthreads();   // staging visible to all waves

    bf16x8 fa[4], fb[4];
#pragma unroll
    for (int i = 0; i < 4; ++i)
      fa[i] = *(const bf16x8*)(As + (wm + i * 16 + lr) * BK + quad * 8);
#pragma unroll
    for (int j = 0; j < 4; ++j)
      fb[j] = *(const bf16x8*)(Bs + (wn + j * 16 + lr) * BK + quad * 8);

#pragma unroll
    for (int i = 0; i < 4; ++i)
#pragma unroll
      for (int j = 0; j < 4; ++j)
        acc[i][j] = __builtin_amdgcn_mfma_f32_16x16x32_bf16(
            fa[i], fb[j], acc[i][j], 0, 0, 0);
  }

  // epilogue: C/D layout col=lane&15, row=quad*4+reg (m89-verified); f32 out
#pragma unroll
  for (int i = 0; i < 4; ++i)
#pragma unroll
    for (int j = 0; j < 4; ++j)
#pragma unroll
      for (int r = 0; r < 4; ++r) {
        const int row = m0 + wm + i * 16 + (quad << 2) + r;
        const int col = n0 + wn + j * 16 + lr;
        C[(size_t)row * OUT_F + col] = acc[i][j][r];
      }
}

extern "C" void kernel_launch(void* const* d_in, const int* in_sizes, int n_in,
                              void* d_out, int out_size, void* d_ws, size_t ws_size,
                              hipStream_t stream) {
  const float* x   = (const float*)d_in[0];   // fp16 in reference -> f32 here
  const int* qw    = (const int*)d_in[1];
  const int* am1   = (const int*)d_in[2];
  const float* cd1 = (const float*)d_in[3];
  const float* of1 = (const float*)d_in[4];
  const float* am2 = (const float*)d_in[5];
  const float* cd2 = (const float*)d_in[6];
  bf16_t* W  = (bf16_t*)d_ws;     // 4096*4096*2 = 32 MiB scratch
  float* out = (float*)d_out;     // fp16 in reference -> f32 here

  dequant_nf4<<<dim3((OUT_F * IN_F) / 8 / 256), dim3(256), 0, stream>>>(
      qw, am1, cd1, of1, am2, cd2, W);

  dim3 grid(OUT_F / BN, TOKENS / BM);   // (32, 64) = 2048 blocks
  gemm_xwt<<<grid, dim3(256), 0, stream>>>(x, W, out);
}

// Round 4
// 624.553 us; speedup vs baseline: 1.0024x; 1.0024x over previous
//
#include <hip/hip_runtime.h>
#include <hip/hip_bf16.h>
#include <cstdint>
#include <cstddef>

typedef __bf16 bf16_t;
typedef __bf16 bf16x8 __attribute__((ext_vector_type(8)));
typedef float f32x4 __attribute__((ext_vector_type(4)));

#define TOKENS 8192
#define IN_F 4096
#define OUT_F 4096

#define BM 128
#define BN 128
#define BK 32

// async global->LDS, 16B per lane; LDS dest is wave-uniform base + lane*16
#define GLDS(gp, lp)                                                      \
  __builtin_amdgcn_global_load_lds(                                       \
      (__attribute__((address_space(1))) void*)(gp),                      \
      (__attribute__((address_space(3))) void*)(lp), 16, 0, 0)

// ---------------- dequant: packed nibbles -> bf16 W[OUT_F][IN_F] ----------
__global__ __launch_bounds__(256) void dequant_nf4(
    const int* __restrict__ qw, const int* __restrict__ am1,
    const float* __restrict__ cd1, const float* __restrict__ of1,
    const float* __restrict__ am2, const float* __restrict__ cd2,
    bf16_t* __restrict__ W) {
  const int t = blockIdx.x * 256 + threadIdx.x;
  const int e0 = t << 3;        // 8 dequantized elements per thread
  const int b1 = e0 >> 6;       // primary block (64 elems) -- all 8 share it
  const int b2 = e0 >> 8;       // secondary block (256 elems)
  const int4 v = *(const int4*)(qw + (t << 2));
  const float s2 = am2[b2] / cd2[b2];
  const float s1 = ((float)am1[b1] / cd1[b1]) * s2;
  const float off = of1[b1];
  int vv[4] = {v.x, v.y, v.z, v.w};
  bf16x8 w;
#pragma unroll
  for (int i = 0; i < 4; ++i) {
    // even linear offset = lower nibble, odd = upper nibble
    w[2 * i]     = (bf16_t)(((float)(vv[i] & 15) - off) * s1);
    w[2 * i + 1] = (bf16_t)(((float)((vv[i] >> 4) & 15) - off) * s1);
  }
  *(bf16x8*)(W + e0) = w;
}

// ---------------- X: f32 -> bf16 one-shot convert -------------------------
__global__ __launch_bounds__(256) void conv_x(
    const float* __restrict__ X, bf16_t* __restrict__ Xb) {
  const size_t e0 = ((size_t)blockIdx.x * 256 + threadIdx.x) << 3;
  f32x4 a = *(const f32x4*)(X + e0);
  f32x4 b = *(const f32x4*)(X + e0 + 4);
  bf16x8 w;
#pragma unroll
  for (int i = 0; i < 4; ++i) {
    w[i] = (bf16_t)a[i];
    w[i + 4] = (bf16_t)b[i];
  }
  *(bf16x8*)(Xb + e0) = w;
}

// ------- GEMM (fast): C[M,N] = Xb[M,K] * W[N,K]^T, bf16 in, f32 out -------
// m97 structure: global_load_lds width-16 staging, 128x128 tile, BK=32.
__global__ __launch_bounds__(256) void gemm_bb(
    const bf16_t* __restrict__ X, const bf16_t* __restrict__ W,
    float* __restrict__ C) {
  // row-major tiles, stride BK (=64B) -- contiguous for global_load_lds
  __shared__ __align__(16) bf16_t As[BM * BK];
  __shared__ __align__(16) bf16_t Bs[BN * BK];

  const int tid = threadIdx.x;
  const int lane = tid & 63;
  const int wid = tid >> 6;       // 4 waves
  const int m0 = blockIdx.y * BM;
  const int n0 = blockIdx.x * BN;

  // staging: wave w covers rows 16w..16w+15 per round; lane l -> row +l/4,
  // col (l&3)*8 bf16. Two rounds per tile (rows 0..63, 64..127).
  const int srow = (wid << 4) + (lane >> 2);
  const int scol = (lane & 3) << 3;
  const bf16_t* ag0 = X + (size_t)(m0 + srow) * IN_F + scol;
  const bf16_t* ag1 = ag0 + (size_t)64 * IN_F;
  const bf16_t* bg0 = W + (size_t)(n0 + srow) * IN_F + scol;
  const bf16_t* bg1 = bg0 + (size_t)64 * IN_F;

  bf16_t* al0 = As + (wid << 9);      // wave-uniform LDS base
  bf16_t* al1 = al0 + 64 * BK;
  bf16_t* bl0 = Bs + (wid << 9);
  bf16_t* bl1 = bl0 + 64 * BK;

  // wave 2x2 grid over the 128x128 tile; 4x4 MFMA tiles of 16x16 per wave
  const int wm = (wid >> 1) << 6;
  const int wn = (wid & 1) << 6;
  const int lr = lane & 15;
  const int quad = lane >> 4;

  f32x4 acc[4][4] = {};

  for (int k0 = 0; k0 < IN_F; k0 += BK) {
    GLDS(ag0 + k0, al0);
    GLDS(ag1 + k0, al1);
    GLDS(bg0 + k0, bl0);
    GLDS(bg1 + k0, bl1);
    __syncthreads();   // vmcnt(0) drain + barrier

    bf16x8 fa[4], fb[4];
#pragma unroll
    for (int i = 0; i < 4; ++i)
      fa[i] = *(const bf16x8*)(As + (wm + i * 16 + lr) * BK + quad * 8);
#pragma unroll
    for (int j = 0; j < 4; ++j)
      fb[j] = *(const bf16x8*)(Bs + (wn + j * 16 + lr) * BK + quad * 8);

#pragma unroll
    for (int i = 0; i < 4; ++i)
#pragma unroll
      for (int j = 0; j < 4; ++j)
        acc[i][j] = __builtin_amdgcn_mfma_f32_16x16x32_bf16(
            fa[i], fb[j], acc[i][j], 0, 0, 0);
    __syncthreads();
  }

  // epilogue: C/D layout col=lane&15, row=quad*4+reg; f32 out
#pragma unroll
  for (int i = 0; i < 4; ++i)
#pragma unroll
    for (int j = 0; j < 4; ++j)
#pragma unroll
      for (int r = 0; r < 4; ++r) {
        const int row = m0 + wm + i * 16 + (quad << 2) + r;
        const int col = n0 + wn + j * 16 + lr;
        C[(size_t)row * OUT_F + col] = acc[i][j][r];
      }
}

// ------- GEMM (fallback, round-3 passing kernel): X f32, W bf16 -----------
__global__ __launch_bounds__(256) void gemm_fb(
    const float* __restrict__ X, const bf16_t* __restrict__ W,
    float* __restrict__ C) {
  __shared__ __align__(16) bf16_t As[BM * BK];
  __shared__ __align__(16) bf16_t Bs[BN * BK];

  const int tid = threadIdx.x;
  const int lane = tid & 63;
  const int wid = tid >> 6;
  const int m0 = blockIdx.y * BM;
  const int n0 = blockIdx.x * BN;

  const int srow = tid >> 2;
  const int sk = (tid & 3) << 3;
  const float* ag0 = X + (size_t)(m0 + srow) * IN_F + sk;
  const float* ag1 = ag0 + (size_t)64 * IN_F;
  const bf16_t* bg0 = W + (size_t)(n0 + srow) * IN_F + sk;
  const bf16_t* bg1 = bg0 + (size_t)64 * IN_F;
  bf16_t* as0 = As + srow * BK + sk;
  bf16_t* as1 = as0 + 64 * BK;
  bf16_t* bs0 = Bs + srow * BK + sk;
  bf16_t* bs1 = bs0 + 64 * BK;

  const int wm = (wid >> 1) << 6;
  const int wn = (wid & 1) << 6;
  const int lr = lane & 15;
  const int quad = lane >> 4;

  f32x4 acc[4][4] = {};

  for (int k0 = 0; k0 < IN_F; k0 += BK) {
    f32x4 xa0 = *(const f32x4*)(ag0 + k0);
    f32x4 xa1 = *(const f32x4*)(ag0 + k0 + 4);
    f32x4 xb0 = *(const f32x4*)(ag1 + k0);
    f32x4 xb1 = *(const f32x4*)(ag1 + k0 + 4);
    bf16x8 rb0 = *(const bf16x8*)(bg0 + k0);
    bf16x8 rb1 = *(const bf16x8*)(bg1 + k0);

    bf16x8 ra0, ra1;
#pragma unroll
    for (int t = 0; t < 4; ++t) {
      ra0[t] = (bf16_t)xa0[t];
      ra0[t + 4] = (bf16_t)xa1[t];
      ra1[t] = (bf16_t)xb0[t];
      ra1[t + 4] = (bf16_t)xb1[t];
    }

    __syncthreads();
    *(bf16x8*)as0 = ra0;
    *(bf16x8*)as1 = ra1;
    *(bf16x8*)bs0 = rb0;
    *(bf16x8*)bs1 = rb1;
    __syncthreads();

    bf16x8 fa[4], fb[4];
#pragma unroll
    for (int i = 0; i < 4; ++i)
      fa[i] = *(const bf16x8*)(As + (wm + i * 16 + lr) * BK + quad * 8);
#pragma unroll
    for (int j = 0; j < 4; ++j)
      fb[j] = *(const bf16x8*)(Bs + (wn + j * 16 + lr) * BK + quad * 8);

#pragma unroll
    for (int i = 0; i < 4; ++i)
#pragma unroll
      for (int j = 0; j < 4; ++j)
        acc[i][j] = __builtin_amdgcn_mfma_f32_16x16x32_bf16(
            fa[i], fb[j], acc[i][j], 0, 0, 0);
  }

#pragma unroll
  for (int i = 0; i < 4; ++i)
#pragma unroll
    for (int j = 0; j < 4; ++j)
#pragma unroll
      for (int r = 0; r < 4; ++r) {
        const int row = m0 + wm + i * 16 + (quad << 2) + r;
        const int col = n0 + wn + j * 16 + lr;
        C[(size_t)row * OUT_F + col] = acc[i][j][r];
      }
}

extern "C" void kernel_launch(void* const* d_in, const int* in_sizes, int n_in,
                              void* d_out, int out_size, void* d_ws, size_t ws_size,
                              hipStream_t stream) {
  const float* x   = (const float*)d_in[0];   // fp16 in reference -> f32 here
  const int* qw    = (const int*)d_in[1];
  const int* am1   = (const int*)d_in[2];
  const float* cd1 = (const float*)d_in[3];
  const float* of1 = (const float*)d_in[4];
  const float* am2 = (const float*)d_in[5];
  const float* cd2 = (const float*)d_in[6];
  float* out = (float*)d_out;                 // fp16 in reference -> f32 here

  const size_t W_BYTES  = (size_t)OUT_F * IN_F * 2;   // 32 MiB
  const size_t XB_BYTES = (size_t)TOKENS * IN_F * 2;  // 64 MiB
  bf16_t* W = (bf16_t*)d_ws;

  dequant_nf4<<<dim3((OUT_F * IN_F) / 8 / 256), dim3(256), 0, stream>>>(
      qw, am1, cd1, of1, am2, cd2, W);

  dim3 grid(OUT_F / BN, TOKENS / BM);   // (32, 64) = 2048 blocks

  if (ws_size >= W_BYTES + XB_BYTES) {
    // fast path: pre-convert X to bf16, GLDS GEMM (m97 structure)
    bf16_t* Xb = (bf16_t*)((char*)d_ws + W_BYTES);
    conv_x<<<dim3((TOKENS * IN_F) / 8 / 256), dim3(256), 0, stream>>>(x, Xb);
    gemm_bb<<<grid, dim3(256), 0, stream>>>(Xb, W, out);
  } else {
    // fallback: round-3 passing kernel (f32 X converted at staging)
    gemm_fb<<<grid, dim3(256), 0, stream>>>(x, W, out);
  }
}

// Round 5
// 556.357 us; speedup vs baseline: 1.1252x; 1.1226x over previous
//
#include <hip/hip_runtime.h>
#include <hip/hip_bf16.h>
#include <cstdint>
#include <cstddef>

typedef __bf16 bf16_t;
typedef __bf16 bf16x8 __attribute__((ext_vector_type(8)));
typedef float f32x4 __attribute__((ext_vector_type(4)));

#define TOKENS 8192
#define IN_F 4096
#define OUT_F 4096

#define BM 128
#define BN 128
#define BK 32

// async global->LDS, 16B per lane; LDS dest is wave-uniform base + lane*16
#define GLDS(gp, lp)                                                      \
  __builtin_amdgcn_global_load_lds(                                       \
      (__attribute__((address_space(1))) void*)(gp),                      \
      (__attribute__((address_space(3))) void*)(lp), 16, 0, 0)

// ---------------- dequant: packed nibbles -> bf16 W[OUT_F][IN_F] ----------
__global__ __launch_bounds__(256) void dequant_nf4(
    const int* __restrict__ qw, const int* __restrict__ am1,
    const float* __restrict__ cd1, const float* __restrict__ of1,
    const float* __restrict__ am2, const float* __restrict__ cd2,
    bf16_t* __restrict__ W) {
  const int t = blockIdx.x * 256 + threadIdx.x;
  const int e0 = t << 3;        // 8 dequantized elements per thread
  const int b1 = e0 >> 6;       // primary block (64 elems) -- all 8 share it
  const int b2 = e0 >> 8;       // secondary block (256 elems)
  const int4 v = *(const int4*)(qw + (t << 2));
  const float s2 = am2[b2] / cd2[b2];
  const float s1 = ((float)am1[b1] / cd1[b1]) * s2;
  const float off = of1[b1];
  int vv[4] = {v.x, v.y, v.z, v.w};
  bf16x8 w;
#pragma unroll
  for (int i = 0; i < 4; ++i) {
    // even linear offset = lower nibble, odd = upper nibble
    w[2 * i]     = (bf16_t)(((float)(vv[i] & 15) - off) * s1);
    w[2 * i + 1] = (bf16_t)(((float)((vv[i] >> 4) & 15) - off) * s1);
  }
  *(bf16x8*)(W + e0) = w;
}

// ---------------- X: f32 -> bf16 one-shot convert -------------------------
__global__ __launch_bounds__(256) void conv_x(
    const float* __restrict__ X, bf16_t* __restrict__ Xb) {
  const size_t e0 = ((size_t)blockIdx.x * 256 + threadIdx.x) << 3;
  f32x4 a = *(const f32x4*)(X + e0);
  f32x4 b = *(const f32x4*)(X + e0 + 4);
  bf16x8 w;
#pragma unroll
  for (int i = 0; i < 4; ++i) {
    w[i] = (bf16_t)a[i];
    w[i + 4] = (bf16_t)b[i];
  }
  *(bf16x8*)(Xb + e0) = w;
}

// ------- GEMM (fast): C[M,N] = Xb[M,K] * W[N,K]^T, bf16 in, f32 out -------
// m97 structure: global_load_lds width-16 staging, 128x128 tile, BK=32.
// __launch_bounds__(256,4): force total regs <= 128 (64 acc AGPR + 64 arch)
// so 4 blocks/CU stay resident -- round-4 regression was occupancy 39.7->21.9
// when the GLDS variant compiled to 88+64 regs (3 waves/EU).
__global__ __launch_bounds__(256, 4) void gemm_bb(
    const bf16_t* __restrict__ X, const bf16_t* __restrict__ W,
    float* __restrict__ C) {
  // row-major tiles, stride BK (=64B) -- contiguous for global_load_lds
  __shared__ __align__(16) bf16_t As[BM * BK];
  __shared__ __align__(16) bf16_t Bs[BN * BK];

  const int tid = threadIdx.x;
  const int lane = tid & 63;
  const int wid = tid >> 6;       // 4 waves
  const int m0 = blockIdx.y * BM;
  const int n0 = blockIdx.x * BN;

  // staging: wave w covers rows 16w..16w+15 per round; lane l -> row +l/4,
  // col (l&3)*8 bf16. Two rounds per tile (rows 0..63, 64..127).
  const int srow = (wid << 4) + (lane >> 2);
  const int scol = (lane & 3) << 3;
  const bf16_t* ag0 = X + (size_t)(m0 + srow) * IN_F + scol;
  const bf16_t* ag1 = ag0 + (size_t)64 * IN_F;
  const bf16_t* bg0 = W + (size_t)(n0 + srow) * IN_F + scol;
  const bf16_t* bg1 = bg0 + (size_t)64 * IN_F;

  bf16_t* al0 = As + (wid << 9);      // wave-uniform LDS base
  bf16_t* al1 = al0 + 64 * BK;
  bf16_t* bl0 = Bs + (wid << 9);
  bf16_t* bl1 = bl0 + 64 * BK;

  // wave 2x2 grid over the 128x128 tile; 4x4 MFMA tiles of 16x16 per wave
  const int wm = (wid >> 1) << 6;
  const int wn = (wid & 1) << 6;
  const int lr = lane & 15;
  const int quad = lane >> 4;

  f32x4 acc[4][4] = {};

  for (int k0 = 0; k0 < IN_F; k0 += BK) {
    GLDS(ag0 + k0, al0);
    GLDS(ag1 + k0, al1);
    GLDS(bg0 + k0, bl0);
    GLDS(bg1 + k0, bl1);
    __syncthreads();   // vmcnt(0) drain + barrier

    bf16x8 fa[4], fb[4];
#pragma unroll
    for (int i = 0; i < 4; ++i)
      fa[i] = *(const bf16x8*)(As + (wm + i * 16 + lr) * BK + quad * 8);
#pragma unroll
    for (int j = 0; j < 4; ++j)
      fb[j] = *(const bf16x8*)(Bs + (wn + j * 16 + lr) * BK + quad * 8);

#pragma unroll
    for (int i = 0; i < 4; ++i)
#pragma unroll
      for (int j = 0; j < 4; ++j)
        acc[i][j] = __builtin_amdgcn_mfma_f32_16x16x32_bf16(
            fa[i], fb[j], acc[i][j], 0, 0, 0);
    __syncthreads();
  }

  // epilogue: C/D layout col=lane&15, row=quad*4+reg; f32 out
#pragma unroll
  for (int i = 0; i < 4; ++i)
#pragma unroll
    for (int j = 0; j < 4; ++j)
#pragma unroll
      for (int r = 0; r < 4; ++r) {
        const int row = m0 + wm + i * 16 + (quad << 2) + r;
        const int col = n0 + wn + j * 16 + lr;
        C[(size_t)row * OUT_F + col] = acc[i][j][r];
      }
}

// ------- GEMM (fallback, round-3 passing kernel): X f32, W bf16 -----------
__global__ __launch_bounds__(256) void gemm_fb(
    const float* __restrict__ X, const bf16_t* __restrict__ W,
    float* __restrict__ C) {
  __shared__ __align__(16) bf16_t As[BM * BK];
  __shared__ __align__(16) bf16_t Bs[BN * BK];

  const int tid = threadIdx.x;
  const int lane = tid & 63;
  const int wid = tid >> 6;
  const int m0 = blockIdx.y * BM;
  const int n0 = blockIdx.x * BN;

  const int srow = tid >> 2;
  const int sk = (tid & 3) << 3;
  const float* ag0 = X + (size_t)(m0 + srow) * IN_F + sk;
  const float* ag1 = ag0 + (size_t)64 * IN_F;
  const bf16_t* bg0 = W + (size_t)(n0 + srow) * IN_F + sk;
  const bf16_t* bg1 = bg0 + (size_t)64 * IN_F;
  bf16_t* as0 = As + srow * BK + sk;
  bf16_t* as1 = as0 + 64 * BK;
  bf16_t* bs0 = Bs + srow * BK + sk;
  bf16_t* bs1 = bs0 + 64 * BK;

  const int wm = (wid >> 1) << 6;
  const int wn = (wid & 1) << 6;
  const int lr = lane & 15;
  const int quad = lane >> 4;

  f32x4 acc[4][4] = {};

  for (int k0 = 0; k0 < IN_F; k0 += BK) {
    f32x4 xa0 = *(const f32x4*)(ag0 + k0);
    f32x4 xa1 = *(const f32x4*)(ag0 + k0 + 4);
    f32x4 xb0 = *(const f32x4*)(ag1 + k0);
    f32x4 xb1 = *(const f32x4*)(ag1 + k0 + 4);
    bf16x8 rb0 = *(const bf16x8*)(bg0 + k0);
    bf16x8 rb1 = *(const bf16x8*)(bg1 + k0);

    bf16x8 ra0, ra1;
#pragma unroll
    for (int t = 0; t < 4; ++t) {
      ra0[t] = (bf16_t)xa0[t];
      ra0[t + 4] = (bf16_t)xa1[t];
      ra1[t] = (bf16_t)xb0[t];
      ra1[t + 4] = (bf16_t)xb1[t];
    }

    __syncthreads();
    *(bf16x8*)as0 = ra0;
    *(bf16x8*)as1 = ra1;
    *(bf16x8*)bs0 = rb0;
    *(bf16x8*)bs1 = rb1;
    __syncthreads();

    bf16x8 fa[4], fb[4];
#pragma unroll
    for (int i = 0; i < 4; ++i)
      fa[i] = *(const bf16x8*)(As + (wm + i * 16 + lr) * BK + quad * 8);
#pragma unroll
    for (int j = 0; j < 4; ++j)
      fb[j] = *(const bf16x8*)(Bs + (wn + j * 16 + lr) * BK + quad * 8);

#pragma unroll
    for (int i = 0; i < 4; ++i)
#pragma unroll
      for (int j = 0; j < 4; ++j)
        acc[i][j] = __builtin_amdgcn_mfma_f32_16x16x32_bf16(
            fa[i], fb[j], acc[i][j], 0, 0, 0);
  }

#pragma unroll
  for (int i = 0; i < 4; ++i)
#pragma unroll
    for (int j = 0; j < 4; ++j)
#pragma unroll
      for (int r = 0; r < 4; ++r) {
        const int row = m0 + wm + i * 16 + (quad << 2) + r;
        const int col = n0 + wn + j * 16 + lr;
        C[(size_t)row * OUT_F + col] = acc[i][j][r];
      }
}

extern "C" void kernel_launch(void* const* d_in, const int* in_sizes, int n_in,
                              void* d_out, int out_size, void* d_ws, size_t ws_size,
                              hipStream_t stream) {
  const float* x   = (const float*)d_in[0];   // fp16 in reference -> f32 here
  const int* qw    = (const int*)d_in[1];
  const int* am1   = (const int*)d_in[2];
  const float* cd1 = (const float*)d_in[3];
  const float* of1 = (const float*)d_in[4];
  const float* am2 = (const float*)d_in[5];
  const float* cd2 = (const float*)d_in[6];
  float* out = (float*)d_out;                 // fp16 in reference -> f32 here

  const size_t W_BYTES  = (size_t)OUT_F * IN_F * 2;   // 32 MiB
  const size_t XB_BYTES = (size_t)TOKENS * IN_F * 2;  // 64 MiB
  bf16_t* W = (bf16_t*)d_ws;

  dequant_nf4<<<dim3((OUT_F * IN_F) / 8 / 256), dim3(256), 0, stream>>>(
      qw, am1, cd1, of1, am2, cd2, W);

  dim3 grid(OUT_F / BN, TOKENS / BM);   // (32, 64) = 2048 blocks

  if (ws_size >= W_BYTES + XB_BYTES) {
    // fast path: pre-convert X to bf16, GLDS GEMM (m97 structure)
    bf16_t* Xb = (bf16_t*)((char*)d_ws + W_BYTES);
    conv_x<<<dim3((TOKENS * IN_F) / 8 / 256), dim3(256), 0, stream>>>(x, Xb);
    gemm_bb<<<grid, dim3(256), 0, stream>>>(Xb, W, out);
  } else {
    // fallback: round-3 passing kernel (f32 X converted at staging)
    gemm_fb<<<grid, dim3(256), 0, stream>>>(x, W, out);
  }
}